// Round 1
// baseline (94.799 us; speedup 1.0000x reference)
//
#include <hip/hip_runtime.h>
#include <math.h>

#define NC 5
#define EPS_F 0.1f

// One thread per row. q = x·Wᵀ + b (all > 0). Solve
//   min KL(p||q) s.t. KL(p||u) <= eps  on the simplex
// closed-form path p(t) = softmax(t · log q), t = 1/(1+lam).
// f(t) = KL(p(t)||u) - eps = t·E_p[u] - log Z + log n - eps  (u = s - max s)
// f'(t) = t·Var_p(u). Bracketed Newton on t in [0,1].
__global__ __launch_bounds__(256) void klproj_kernel(
    const float* __restrict__ x,
    const float* __restrict__ W,
    const float* __restrict__ b,
    float* __restrict__ out,
    int batch)
{
    int row = blockIdx.x * blockDim.x + threadIdx.x;
    if (row >= batch) return;

    // --- load x row (20 B/thread, contiguous across the wave) ---
    float xv[NC];
#pragma unroll
    for (int k = 0; k < NC; ++k) xv[k] = x[row * NC + k];

    // --- q_j = sum_k x_k W[j][k] + b_j ; s_j = log q_j (W,b uniform -> s_loads)
    float s[NC];
    float m = -1e30f;
#pragma unroll
    for (int j = 0; j < NC; ++j) {
        float q = b[j];
#pragma unroll
        for (int k = 0; k < NC; ++k) q = fmaf(xv[k], W[j * NC + k], q);
        float sj = __logf(q);
        s[j] = sj;
        m = fmaxf(m, sj);
    }
    float u[NC];
#pragma unroll
    for (int j = 0; j < NC; ++j) u[j] = s[j] - m;

    const float logn = 1.6094379124341003f; // log(5)

    // f(t), f'(t) from one pass of exps
    auto eval = [&](float t, float& f, float& fp) {
        float Z = 0.f, T1 = 0.f, T2 = 0.f;
#pragma unroll
        for (int j = 0; j < NC; ++j) {
            float ej = __expf(t * u[j]);
            Z += ej;
            T1 = fmaf(ej, u[j], T1);
            T2 = fmaf(ej, u[j] * u[j], T2);
        }
        float rZ = 1.0f / Z;
        float Eu = T1 * rZ;
        float Eu2 = T2 * rZ;
        f  = fmaf(t, Eu, -__logf(Z)) + (logn - EPS_F);
        fp = t * (Eu2 - Eu * Eu);
    };

    // feasibility at t=1 (lam=0)
    float f1, fp1;
    eval(1.0f, f1, fp1);

    float t = 1.0f;
    if (f1 > 0.f) {
        float lo = 0.f, hi = 1.0f;
        // Newton start from the t=1 evaluation
        float cand = 1.0f - f1 / fp1;
        // NaN-safe bracket guard (inverted-compare form)
        t = (cand > lo && cand < hi) ? cand : 0.5f;
#pragma unroll
        for (int it = 0; it < 8; ++it) {
            float f, fp;
            eval(t, f, fp);
            if (f > 0.f) hi = t; else lo = t;
            float tn = t - f / fp;
            t = (tn > lo && tn < hi) ? tn : 0.5f * (lo + hi);
        }
    }

    // final p = softmax(t·u)
    float e[NC], Z = 0.f;
#pragma unroll
    for (int j = 0; j < NC; ++j) { e[j] = __expf(t * u[j]); Z += e[j]; }
    float rZ = 1.0f / Z;
#pragma unroll
    for (int j = 0; j < NC; ++j) out[row * NC + j] = e[j] * rZ;
}

extern "C" void kernel_launch(void* const* d_in, const int* in_sizes, int n_in,
                              void* d_out, int out_size, void* d_ws, size_t ws_size,
                              hipStream_t stream) {
    const float* x = (const float*)d_in[0];
    const float* W = (const float*)d_in[1];
    const float* b = (const float*)d_in[2];
    float* out = (float*)d_out;
    int batch = in_sizes[0] / NC;

    int block = 256;
    int grid = (batch + block - 1) / block;
    klproj_kernel<<<grid, block, 0, stream>>>(x, W, b, out, batch);
}